// Round 1
// baseline (152.694 us; speedup 1.0000x reference)
//
#include <hip/hip_runtime.h>
#include <stdint.h>

#define D      10000
#define WPR    313        // ceil(10000/32) words per hypervector row
#define NPIX   784
#define NB     64
#define NC     10
#define NPC    8          // p-chunks for the count kernel
#define PCL    98         // pixels per chunk (8*98 = 784), fits 7-bit counter

// Pack sign bits of a [nrows x 10000] float matrix into [nrows x 313] uint32.
// bit = 1  <=>  value < 0 (i.e. value == -1). Pad d >= 10000 with bit 0.
__global__ __launch_bounds__(256) void pack_bits(const float* __restrict__ src,
                                                 uint32_t* __restrict__ dst) {
    int row = blockIdx.x;
    const float* s = src + (size_t)row * D;
    uint32_t* d = dst + (size_t)row * WPR;
    for (int i = threadIdx.x; i < WPR * 32; i += 256) {
        float v = (i < D) ? s[i] : 1.0f;
        unsigned long long m = __ballot(v < 0.0f);
        if ((i & 63) == 0)       d[i >> 5] = (uint32_t)m;
        else if ((i & 63) == 32) d[i >> 5] = (uint32_t)(m >> 32);
    }
}

// For each (b, word w, p-chunk): count, per bit-lane d, how many p in the chunk
// have lev[idx[b,p],d] * pos[p,d] == -1 (xor of sign bits). Bit-sliced ripple
// counter: 7 slices (count <= 98 < 128). Output byte-packed, layout
// partial[pc][b][q][w] with q = d-quad (4 counts per uint32) for coalesced I/O.
__global__ __launch_bounds__(64) void count_kernel(const float* __restrict__ x,
                                                   const uint32_t* __restrict__ Lp,
                                                   const uint32_t* __restrict__ Pp,
                                                   uint32_t* __restrict__ partial) {
    int tid = threadIdx.x;
    int b = blockIdx.y, pc = blockIdx.z;
    int w = blockIdx.x * 64 + tid;
    int p0 = pc * PCL;

    __shared__ int idxs[PCL];
    for (int i = tid; i < PCL; i += 64) {
        float xv = x[b * NPIX + p0 + i];
        int v = (int)rintf(xv * 255.0f);     // round-half-even == jnp.round
        v = v < 0 ? 0 : (v > 255 ? 255 : v);
        idxs[i] = v;
    }
    __syncthreads();
    if (w >= WPR) return;

    uint32_t s0 = 0, s1 = 0, s2 = 0, s3 = 0, s4 = 0, s5 = 0, s6 = 0;
    const uint32_t* pp = Pp + (size_t)p0 * WPR + w;
    for (int i = 0; i < PCL; ++i) {
        uint32_t xw = Lp[(size_t)idxs[i] * WPR + w] ^ pp[(size_t)i * WPR];
        uint32_t c = xw, t;
        t = s0 & c; s0 ^= c; c = t;
        t = s1 & c; s1 ^= c; c = t;
        t = s2 & c; s2 ^= c; c = t;
        t = s3 & c; s3 ^= c; c = t;
        t = s4 & c; s4 ^= c; c = t;
        t = s5 & c; s5 ^= c; c = t;
        s6 ^= c;                              // no carry-out possible (<=98)
    }

    uint32_t* out = partial + (((size_t)pc * NB + b) * 8) * WPR + w;
    #pragma unroll
    for (int q = 0; q < 8; ++q) {
        uint32_t word = 0;
        #pragma unroll
        for (int r = 0; r < 4; ++r) {
            int j = q * 4 + r;
            uint32_t cnt = ((s0 >> j) & 1u)        | (((s1 >> j) & 1u) << 1)
                         | (((s2 >> j) & 1u) << 2) | (((s3 >> j) & 1u) << 3)
                         | (((s4 >> j) & 1u) << 4) | (((s5 >> j) & 1u) << 5)
                         | (((s6 >> j) & 1u) << 6);
            word |= cnt << (8 * r);
        }
        out[(size_t)q * WPR] = word;          // lanes stride 4B: coalesced
    }
}

// Sum 8 p-chunk partial counts per (b,d); enc = (784 - 2*cnt > 0) ? +1 : -1;
// fused tiny GEMV against classify_weight with shuffle-reduce + atomicAdd.
__global__ __launch_bounds__(256) void logits_kernel(const uint32_t* __restrict__ partial,
                                                     const float* __restrict__ cw,
                                                     float* __restrict__ out) {
    int b = blockIdx.y;
    int base = blockIdx.x * 2560;
    int tid = threadIdx.x;
    float acc[NC];
    #pragma unroll
    for (int c = 0; c < NC; ++c) acc[c] = 0.0f;

    int dend = base + 2560; if (dend > D) dend = D;
    for (int d = base + tid; d < dend; d += 256) {
        int w = d >> 5, j = d & 31, q = j >> 2, r = j & 3;
        int sum = 0;
        #pragma unroll
        for (int pc = 0; pc < NPC; ++pc)
            sum += (int)((partial[(((size_t)pc * NB + b) * 8 + q) * WPR + w] >> (8 * r)) & 0xffu);
        float enc = (sum < 392) ? 1.0f : -1.0f;   // 784 - 2*sum > 0
        #pragma unroll
        for (int c = 0; c < NC; ++c) acc[c] += enc * cw[(size_t)c * D + d];
    }

    int lane = tid & 63;
    #pragma unroll
    for (int c = 0; c < NC; ++c) {
        float v = acc[c];
        #pragma unroll
        for (int off = 32; off > 0; off >>= 1) v += __shfl_down(v, off, 64);
        if (lane == 0) atomicAdd(&out[b * NC + c], v);
    }
}

extern "C" void kernel_launch(void* const* d_in, const int* in_sizes, int n_in,
                              void* d_out, int out_size, void* d_ws, size_t ws_size,
                              hipStream_t stream) {
    const float* x   = (const float*)d_in[0];   // [64, 28, 28]
    const float* pos = (const float*)d_in[1];   // [784, 10000]
    const float* lev = (const float*)d_in[2];   // [256, 10000]
    const float* cw  = (const float*)d_in[3];   // [10, 10000]
    float* out = (float*)d_out;                 // [64, 10] fp32

    uint32_t* Lp      = (uint32_t*)d_ws;        //  256*313 words (320 KB)
    uint32_t* Pp      = Lp + 256 * WPR;         //  784*313 words (981 KB)
    uint32_t* partial = Pp + NPIX * WPR;        //  8*64*8*313 words (5.1 MB)

    hipMemsetAsync(out, 0, (size_t)out_size * sizeof(float), stream);
    pack_bits<<<256, 256, 0, stream>>>(lev, Lp);
    pack_bits<<<NPIX, 256, 0, stream>>>(pos, Pp);
    dim3 g1(5, NB, NPC);                        // 5*64 >= 313 words
    count_kernel<<<g1, 64, 0, stream>>>(x, Lp, Pp, partial);
    dim3 g2(4, NB);
    logits_kernel<<<g2, 256, 0, stream>>>(partial, cw, out);
}

// Round 2
// 112.319 us; speedup vs baseline: 1.3595x; 1.3595x over previous
//
#include <hip/hip_runtime.h>
#include <stdint.h>

#define D      10000
#define WPR    313        // ceil(10000/32) words per hypervector row
#define NPIX   784
#define NB     64
#define NC     10
#define NPC    16         // p-chunks for the count kernel
#define PCL    49         // pixels per chunk (16*49 = 784), fits 6-bit counter

// Pack sign bits of lev [256 x 10000] and pos [784 x 10000] into bitmasks
// (bit=1 <=> value < 0). Thread-per-word: 32 consecutive floats -> 1 uint32,
// via uint4 loads + in-register sign extraction (no cross-lane ops).
// Block 0 additionally zero-inits d_out (so no separate memset dispatch).
__global__ __launch_bounds__(320) void pack_kernel(const float* __restrict__ lev,
                                                   const float* __restrict__ pos,
                                                   uint32_t* __restrict__ Lp,
                                                   uint32_t* __restrict__ Pp,
                                                   float* __restrict__ out) {
    if (blockIdx.x == 0)
        for (int i = threadIdx.x; i < NB * NC; i += 320) out[i] = 0.0f;

    int row = blockIdx.x;             // 0..1039
    const float* src; uint32_t* dst;
    if (row < 256) { src = lev + (size_t)row * D;        dst = Lp + row * WPR; }
    else           { src = pos + (size_t)(row - 256) * D; dst = Pp + (row - 256) * WPR; }

    int w = threadIdx.x;
    if (w >= WPR) return;
    const uint4* p4 = (const uint4*)((const uint32_t*)src + w * 32);
    uint32_t word = 0;
    if (w < WPR - 1) {
        #pragma unroll
        for (int k = 0; k < 8; ++k) {
            uint4 u = p4[k];
            word |= (u.x >> 31) << (4 * k)     | (u.y >> 31) << (4 * k + 1)
                  | (u.z >> 31) << (4 * k + 2) | (u.w >> 31) << (4 * k + 3);
        }
    } else {                           // last word: only 16 valid elements
        #pragma unroll
        for (int k = 0; k < 4; ++k) {
            uint4 u = p4[k];
            word |= (u.x >> 31) << (4 * k)     | (u.y >> 31) << (4 * k + 1)
                  | (u.z >> 31) << (4 * k + 2) | (u.w >> 31) << (4 * k + 3);
        }
    }
    dst[w] = word;
}

// Per (b, word w, p-chunk): count, per bit-lane d, how many p in the chunk have
// lev[idx[b,p],d]*pos[p,d] == -1 (xor of sign bits). 6-slice bit-sliced ripple
// counter (count <= 49). Level row offset goes through readfirstlane so the
// gather is scalar-base + lane-offset (no per-lane 64-bit address mul).
// Output byte-packed: partial[pc][b][q][w], q = d-quad (4 counts per word).
__global__ __launch_bounds__(64) void count_kernel(const float* __restrict__ x,
                                                   const uint32_t* __restrict__ Lp,
                                                   const uint32_t* __restrict__ Pp,
                                                   uint32_t* __restrict__ partial) {
    int tid = threadIdx.x;
    int b = blockIdx.y, pc = blockIdx.z;
    int w = blockIdx.x * 64 + tid;
    int p0 = pc * PCL;

    __shared__ int idxs[PCL];          // pre-multiplied by WPR
    if (tid < PCL) {
        float xv = x[b * NPIX + p0 + tid];
        int v = (int)rintf(xv * 255.0f);   // round-half-even == jnp.round
        v = v < 0 ? 0 : (v > 255 ? 255 : v);
        idxs[tid] = v * WPR;
    }
    __syncthreads();
    if (w >= WPR) return;

    uint32_t s0 = 0, s1 = 0, s2 = 0, s3 = 0, s4 = 0, s5 = 0;
    const uint32_t* pp = Pp + p0 * WPR + w;
    #pragma unroll 7
    for (int i = 0; i < PCL; ++i) {
        int ro = __builtin_amdgcn_readfirstlane(idxs[i]);  // uniform row offset
        uint32_t c = Lp[ro + w] ^ pp[(size_t)i * WPR];
        uint32_t t;
        t = s0 & c; s0 ^= c; c = t;
        t = s1 & c; s1 ^= c; c = t;
        t = s2 & c; s2 ^= c; c = t;
        t = s3 & c; s3 ^= c; c = t;
        t = s4 & c; s4 ^= c; c = t;
        s5 ^= c;                        // counts <= 49 < 64: no carry-out
    }

    uint32_t* o = partial + (((size_t)pc * NB + b) * 8) * WPR + w;
    #pragma unroll
    for (int q = 0; q < 8; ++q) {
        uint32_t word = 0;
        #pragma unroll
        for (int r = 0; r < 4; ++r) {
            int j = q * 4 + r;
            uint32_t cnt = ((s0 >> j) & 1u)        | (((s1 >> j) & 1u) << 1)
                         | (((s2 >> j) & 1u) << 2) | (((s3 >> j) & 1u) << 3)
                         | (((s4 >> j) & 1u) << 4) | (((s5 >> j) & 1u) << 5);
            word |= cnt << (8 * r);
        }
        o[(size_t)q * WPR] = word;      // coalesced across lanes
    }
}

// Sum 16 p-chunk partials per (b,d); enc = sign(784 - 2*cnt); fused tiny GEMV
// against classify_weight. Grid (8, 64) for latency hiding; one atomic per
// (block, class) after wave-shuffle + LDS reduction. out pre-zeroed by pack.
__global__ __launch_bounds__(256) void logits_kernel(const uint32_t* __restrict__ partial,
                                                     const float* __restrict__ cw,
                                                     float* __restrict__ out) {
    int b = blockIdx.y;
    int tid = threadIdx.x;
    int dend = blockIdx.x * 1280 + 1280; if (dend > D) dend = D;
    float acc[NC];
    #pragma unroll
    for (int c = 0; c < NC; ++c) acc[c] = 0.0f;

    for (int d = blockIdx.x * 1280 + tid; d < dend; d += 256) {
        int w = d >> 5, j = d & 31, q = j >> 2, shift = 8 * (j & 3);
        int sum = 0;
        #pragma unroll
        for (int pc = 0; pc < NPC; ++pc)
            sum += (int)((partial[(((size_t)pc * NB + b) * 8 + q) * WPR + w] >> shift) & 0xffu);
        float enc = (2 * sum < NPIX) ? 1.0f : -1.0f;
        #pragma unroll
        for (int c = 0; c < NC; ++c) acc[c] = fmaf(enc, cw[c * D + d], acc[c]);
    }

    int lane = tid & 63, wv = tid >> 6;
    __shared__ float red[4][NC];
    #pragma unroll
    for (int c = 0; c < NC; ++c) {
        float v = acc[c];
        #pragma unroll
        for (int off = 32; off > 0; off >>= 1) v += __shfl_down(v, off, 64);
        if (lane == 0) red[wv][c] = v;
    }
    __syncthreads();
    if (tid < NC) {
        float s = red[0][tid] + red[1][tid] + red[2][tid] + red[3][tid];
        atomicAdd(&out[b * NC + tid], s);
    }
}

extern "C" void kernel_launch(void* const* d_in, const int* in_sizes, int n_in,
                              void* d_out, int out_size, void* d_ws, size_t ws_size,
                              hipStream_t stream) {
    const float* x   = (const float*)d_in[0];   // [64, 28, 28]
    const float* pos = (const float*)d_in[1];   // [784, 10000]
    const float* lev = (const float*)d_in[2];   // [256, 10000]
    const float* cw  = (const float*)d_in[3];   // [10, 10000]
    float* out = (float*)d_out;                 // [64, 10] fp32

    uint32_t* Lp      = (uint32_t*)d_ws;        // 256*313 words (320 KB)
    uint32_t* Pp      = Lp + 256 * WPR;         // 784*313 words (981 KB)
    uint32_t* partial = Pp + NPIX * WPR;        // 16*64*8*313 words (10.3 MB)

    pack_kernel<<<256 + NPIX, 320, 0, stream>>>(lev, pos, Lp, Pp, out);
    dim3 g1(5, NB, NPC);                        // 5*64 = 320 >= 313 words
    count_kernel<<<g1, 64, 0, stream>>>(x, Lp, Pp, partial);
    dim3 g2(8, NB);
    logits_kernel<<<g2, 256, 0, stream>>>(partial, cw, out);
}